// Round 4
// baseline (305.920 us; speedup 1.0000x reference)
//
#include <hip/hip_runtime.h>

constexpr int DEG = 31;        // neighbors per node
constexpr int NEV = 32;        // events per node (self + neighbors)
constexpr int TH  = 16;        // threshold: dp[0..15] + absorbing "over"
constexpr int BLK = 256;       // fallback block size
constexpr int TBL = 1 << 20;   // u8 table entries (padded >= n)

// chunked-LDS kernel geometry
constexpr int CH    = 1 << 16;   // chunk bytes staged to LDS (64 KB)
constexpr int NPASS = TBL / CH;  // 16 passes
constexpr int BLK2  = 1024;      // 16 waves
constexpr int NPB   = 2048;      // nodes per block (2 per thread)

typedef int  vint4  __attribute__((ext_vector_type(4)));   // nt-compatible 16B vector

__global__ void zero_out_kernel(float* out) {
    if (threadIdx.x == 0) out[0] = 0.0f;
}

__device__ __forceinline__ float fast_sigmoid(float x) {
    return 1.0f / (1.0f + __expf(-x));
}

// ---- phase 1: u8 table tbl[i] = rint(sigmoid(gains[i])*255), packed stores ----
// Also zeroes the output scalar.
__global__ __launch_bounds__(256)
void build_table_kernel(const float* __restrict__ gains,
                        unsigned* __restrict__ tbl4,
                        float* __restrict__ out, int n) {
    const int t = blockIdx.x * 256 + threadIdx.x;   // entries 4t..4t+3
    if (t == 0) out[0] = 0.0f;
    if (t < TBL / 4) {
        unsigned w = 0;
        #pragma unroll
        for (int k = 0; k < 4; ++k) {
            const int i = 4 * t + k;
            const float p = (i < n) ? fast_sigmoid(gains[i]) : 0.0f;
            const unsigned b = __float2uint_rn(p * 255.0f);
            w |= (b & 0xFFu) << (8 * k);
        }
        tbl4[t] = w;
    }
}

// Per-node Poisson-binomial DP from the packed u8 probability bytes.
// Event order (self first, then neighbors in j-order) is IDENTICAL to the
// previous passing kernel -> bit-identical per-node results.
__device__ __forceinline__ float node_dp(float g, const unsigned w[8]) {
    const float p0 = fast_sigmoid(g);
    float dp[TH];
    dp[0] = 1.0f;
    #pragma unroll
    for (int k = 1; k < TH; ++k) dp[k] = 0.0f;
    float over = 0.0f;
    #pragma unroll
    for (int j = 0; j < NEV; ++j) {
        float pj;
        if (j == 0) {
            pj = p0;
        } else {
            const unsigned b = (w[(j - 1) >> 2] >> (((j - 1) & 3) * 8)) & 0xFFu;
            pj = (float)b * (1.0f / 255.0f);
        }
        if (j >= TH - 1) over = fmaf(dp[TH - 1], pj, over);
        const int kmax = (j + 1 < TH - 1) ? (j + 1) : (TH - 1);
        #pragma unroll
        for (int k = kmax; k >= 1; --k)
            dp[k] = fmaf(pj, dp[k - 1] - dp[k], dp[k]);
        dp[0] = fmaf(-pj, dp[0], dp[0]);
    }
    return fmaf(0.25f, p0, -over);
}

// ---- phase 2: chunked-LDS gather ----
// r0/r1/r2 established a per-request cap (~0.34 req/cyc/CU ~= 11/cyc/XCD)
// on fine-grained gathers that is insensitive to MLP, L1 policy, and width.
// Fix: stop issuing 31M random requests. Stage the 1 MB table through LDS
// in 16 x 64 KB chunks (coalesced 16 B line-requests: 489 blocks x 1 MB =
// 7.6M line-requests total, 4x fewer than 31M, all coalesced) and serve
// the random byte-gathers from the LDS pipe instead of the L2 path.
// Scan reconstructs packed prob bytes at compile-time j-positions, so the
// final DP is bit-identical to the previous kernel.
__global__ __launch_bounds__(BLK2, 4)
void pgl2_kernel(const float* __restrict__ gains,
                 const int*   __restrict__ nbr,
                 const unsigned char* __restrict__ tbl,
                 float*       __restrict__ out, int n) {
    __shared__ __align__(16) unsigned char smem[CH];   // 64 KB, multi-purpose

    const int tid        = threadIdx.x;
    const int blockStart = blockIdx.x * NPB;
    const int rows_total = min(NPB, n - blockStart);

    // ---- per-thread node indices: A = blockStart+tid, B = +1024 ----
    unsigned idxA[DEG], idxB[DEG];
    #pragma unroll
    for (int j = 0; j < DEG; ++j) { idxA[j] = 0u; idxB[j] = 0u; }

    // ---- bounce neighbor rows through LDS into registers: 4 rounds x 512 rows
    // round r stages rows [r*512, r*512+512); r<2 feeds slot A, r>=2 slot B.
    #pragma unroll
    for (int r = 0; r < 4; ++r) {
        const int rowsR = max(0, min(512, rows_total - r * 512));
        const int elems = rowsR * DEG;
        const int base  = (blockStart + r * 512) * DEG;
        const vint4* nb4 = (const vint4*)(nbr + base);   // base is 16B-aligned (512*31*4 % 16 == 0)
        vint4* s4 = (vint4*)smem;
        const int nvec = elems >> 2;
        for (int v = tid; v < nvec; v += BLK2)
            s4[v] = __builtin_nontemporal_load(nb4 + v);
        for (int e = (nvec << 2) + tid; e < elems; e += BLK2)
            ((int*)smem)[e] = __builtin_nontemporal_load(nbr + base + e);
        __syncthreads();
        const int half = r & 1;
        const int s    = tid - half * 512;
        if (s >= 0 && s < rowsR) {
            const int* row = (const int*)smem + s * DEG;  // stride-31: conflict-free
            if ((r >> 1) == 0) {
                #pragma unroll
                for (int j = 0; j < DEG; ++j) idxA[j] = (unsigned)row[j];
            } else {
                #pragma unroll
                for (int j = 0; j < DEG; ++j) idxB[j] = (unsigned)row[j];
            }
        }
        __syncthreads();
    }

    // ---- pass loop: stage chunk c, scan both nodes' indices ----
    unsigned wA[8], wB[8];
    #pragma unroll
    for (int q = 0; q < 8; ++q) { wA[q] = 0u; wB[q] = 0u; }

    #pragma unroll 1
    for (int c = 0; c < NPASS; ++c) {
        // stage 64 KB chunk: coalesced 16 B cached loads (table reused across
        // blocks -> keep it L2-resident, so NOT nontemporal)
        {
            const vint4* t4 = (const vint4*)(tbl + (size_t)c * CH);
            vint4* s4 = (vint4*)smem;
            #pragma unroll
            for (int q = 0; q < CH / 16 / BLK2; ++q)     // 4 iters
                s4[q * BLK2 + tid] = t4[q * BLK2 + tid];
        }
        __syncthreads();

        const unsigned base = (unsigned)c * (unsigned)CH;
        #pragma unroll
        for (int j = 0; j < DEG; ++j) {
            const unsigned rA = idxA[j] - base;          // unsigned wrap -> exact chunk test
            if (rA < (unsigned)CH)
                wA[j >> 2] |= (unsigned)smem[rA] << ((j & 3) * 8);
            const unsigned rB = idxB[j] - base;
            if (rB < (unsigned)CH)
                wB[j >> 2] |= (unsigned)smem[rB] << ((j & 3) * 8);
        }
        __syncthreads();   // before next chunk overwrites LDS
    }

    // ---- phase B: self gain + DP per owned node ----
    float local = 0.0f;
    const int iA = blockStart + tid;
    const int iB = blockStart + 1024 + tid;
    if (iA < n) local += node_dp(__builtin_nontemporal_load(gains + iA), wA);
    if (iB < n) local += node_dp(__builtin_nontemporal_load(gains + iB), wB);

    // ---- block reduction: wave shuffle -> LDS -> one atomic per block ----
    #pragma unroll
    for (int o = 32; o > 0; o >>= 1) local += __shfl_down(local, o, 64);
    float* s_red = (float*)smem;   // safe: all threads passed the last barrier
    if ((tid & 63) == 0) s_red[tid >> 6] = local;
    __syncthreads();
    if (tid == 0) {
        float s = 0.0f;
        #pragma unroll
        for (int w = 0; w < BLK2 / 64; ++w) s += s_red[w];
        atomicAdd(out, s);
    }
}

// ---- fallback (ws too small): f32 direct gather ----
__global__ __launch_bounds__(BLK)
void pgl_direct_kernel(const float* __restrict__ gains,
                       const int*   __restrict__ nbr,
                       float*       __restrict__ out, int n) {
    __shared__ int s_idx[BLK * DEG];
    __shared__ float s_red[BLK / 64];
    const int tid = threadIdx.x;
    const int blockStart = blockIdx.x * BLK;
    const int rows  = min(BLK, n - blockStart);
    const int elems = rows * DEG;
    const int base  = blockStart * DEG;
    const int4* nb4 = (const int4*)(nbr + base);
    int4* s4 = (int4*)s_idx;
    const int nvec = elems >> 2;
    for (int v = tid; v < nvec; v += BLK) s4[v] = nb4[v];
    for (int e = (nvec << 2) + tid; e < elems; e += BLK) s_idx[e] = nbr[base + e];
    __syncthreads();
    float local = 0.0f;
    const int i = blockStart + tid;
    if (i < n) {
        const int* row = s_idx + tid * DEG;
        float dp[TH];
        dp[0] = 1.0f;
        #pragma unroll
        for (int k = 1; k < TH; ++k) dp[k] = 0.0f;
        float over = 0.0f;
        const float p0 = fast_sigmoid(gains[i]);
        #pragma unroll
        for (int j = 0; j < NEV; ++j) {
            const float pj = (j == 0) ? p0 : fast_sigmoid(gains[row[j - 1]]);
            if (j >= TH - 1) over = fmaf(dp[TH - 1], pj, over);
            const int kmax = (j + 1 < TH - 1) ? (j + 1) : (TH - 1);
            #pragma unroll
            for (int k = kmax; k >= 1; --k)
                dp[k] = fmaf(pj, dp[k - 1] - dp[k], dp[k]);
            dp[0] = fmaf(-pj, dp[0], dp[0]);
        }
        local = fmaf(0.25f, p0, -over);
    }
    #pragma unroll
    for (int o = 32; o > 0; o >>= 1) local += __shfl_down(local, o, 64);
    if ((tid & 63) == 0) s_red[tid >> 6] = local;
    __syncthreads();
    if (tid == 0) {
        float s = 0.0f;
        #pragma unroll
        for (int w = 0; w < BLK / 64; ++w) s += s_red[w];
        atomicAdd(out, s);
    }
}

extern "C" void kernel_launch(void* const* d_in, const int* in_sizes, int n_in,
                              void* d_out, int out_size, void* d_ws, size_t ws_size,
                              hipStream_t stream) {
    const float* gains = (const float*)d_in[0];
    const int*   nbr   = (const int*)d_in[1];
    float*       out   = (float*)d_out;
    const int n = in_sizes[0];

    if (ws_size >= (size_t)TBL && n <= TBL) {
        unsigned char* tbl = (unsigned char*)d_ws;
        build_table_kernel<<<(TBL / 4 + 255) / 256, 256, 0, stream>>>(
            gains, (unsigned*)tbl, out, n);
        const int grid2 = (n + NPB - 1) / NPB;
        pgl2_kernel<<<grid2, BLK2, 0, stream>>>(gains, nbr, tbl, out, n);
    } else {
        zero_out_kernel<<<1, 64, 0, stream>>>(out);
        const int grid = (n + BLK - 1) / BLK;
        pgl_direct_kernel<<<grid, BLK, 0, stream>>>(gains, nbr, out, n);
    }
}